// Round 1
// baseline (5719.797 us; speedup 1.0000x reference)
//
#include <hip/hip_runtime.h>
#include <hip/hip_bf16.h>

using bf16 = __hip_bfloat16;

#define B_   16
#define H_   32
#define W_   32
#define C_   512
#define PC_  256
#define N_   1024   // H*W tokens
#define NTOK 16384  // B*N
#define SCALE_ 0.17677669529663687f
#define EPS_ 1e-5f

#define TM 64
#define TN 64
#define TK 32

__device__ __forceinline__ float b2f(bf16 v){ return __bfloat162float(v); }
__device__ __forceinline__ bf16  f2b(float v){ return __float2bfloat16(v); }

// ---------------------------------------------------------------- zero stats
__global__ void k_zero(float* p, int n){
    int i = blockIdx.x*256 + threadIdx.x;
    if (i < n) p[i] = 0.f;
}

// ---------------------------------------------------------------- qkv = x @ w_qkv^T  (fp32 in, bf16 out)
__global__ __launch_bounds__(256) void k_gemm_qkv(const float* __restrict__ X,
                                                  const float* __restrict__ Wq,
                                                  bf16* __restrict__ out){
    __shared__ float As[TM][TK+1];
    __shared__ float Bs[TN][TK+1];
    int tid = threadIdx.x, tx = tid & 15, ty = tid >> 4;
    int m0 = blockIdx.y*TM, n0 = blockIdx.x*TN;
    float acc[4][4] = {};
    for (int k0 = 0; k0 < C_; k0 += TK){
        for (int e = tid; e < TM*TK; e += 256){
            int kk = e & 31, r = e >> 5;
            As[r][kk] = X[(m0 + r)*C_ + k0 + kk];
        }
        for (int e = tid; e < TN*TK; e += 256){
            int kk = e & 31, r = e >> 5;
            Bs[r][kk] = Wq[(n0 + r)*C_ + k0 + kk];
        }
        __syncthreads();
        #pragma unroll
        for (int kk = 0; kk < TK; ++kk){
            float a[4], b[4];
            #pragma unroll
            for (int i = 0; i < 4; ++i) a[i] = As[ty*4+i][kk];
            #pragma unroll
            for (int j = 0; j < 4; ++j) b[j] = Bs[tx*4+j][kk];
            #pragma unroll
            for (int i = 0; i < 4; ++i)
                #pragma unroll
                for (int j = 0; j < 4; ++j) acc[i][j] += a[i]*b[j];
        }
        __syncthreads();
    }
    #pragma unroll
    for (int i = 0; i < 4; ++i){
        int m = m0 + ty*4 + i;
        #pragma unroll
        for (int j = 0; j < 4; ++j)
            out[m*C_ + n0 + tx*4 + j] = f2b(acc[i][j]);
    }
}

// ------------------------------------------- prevqkv GEMM + fused 2x2 avg/max pool
// GEMM row m enumerates (b, pooled_token g, quadrant q) so the 4 quadrant rows are consecutive.
__global__ __launch_bounds__(256) void k_gemm_prev_pool(const float* __restrict__ PX,
                                                        const float* __restrict__ Wp,
                                                        bf16* __restrict__ avg_o,
                                                        bf16* __restrict__ max_o){
    __shared__ float As[TM][TK+1];
    __shared__ float Bs[TN][TK+1];
    int tid = threadIdx.x, tx = tid & 15, ty = tid >> 4;
    int m0 = blockIdx.y*TM, n0 = blockIdx.x*TN;
    float acc[4][4] = {};
    for (int k0 = 0; k0 < PC_; k0 += TK){
        for (int e = tid; e < TM*TK; e += 256){
            int kk = e & 31, r = e >> 5;
            int m = m0 + r;
            int b = m >> 12, rem = m & 4095;
            int g = rem >> 2, q = rem & 3;
            int i2 = g >> 5, j2 = g & 31;
            int srow = (b*64 + i2*2 + (q>>1))*64 + j2*2 + (q&1);
            As[r][kk] = PX[srow*PC_ + k0 + kk];
        }
        for (int e = tid; e < TN*TK; e += 256){
            int kk = e & 31, r = e >> 5;
            Bs[r][kk] = Wp[(n0 + r)*PC_ + k0 + kk];
        }
        __syncthreads();
        #pragma unroll
        for (int kk = 0; kk < TK; ++kk){
            float a[4], b[4];
            #pragma unroll
            for (int i = 0; i < 4; ++i) a[i] = As[ty*4+i][kk];
            #pragma unroll
            for (int j = 0; j < 4; ++j) b[j] = Bs[tx*4+j][kk];
            #pragma unroll
            for (int i = 0; i < 4; ++i)
                #pragma unroll
                for (int j = 0; j < 4; ++j) acc[i][j] += a[i]*b[j];
        }
        __syncthreads();
    }
    // rows ty*4 .. ty*4+3 are the 4 quadrants of one pooled token
    int g_out = (m0 >> 2) + ty;
    #pragma unroll
    for (int j = 0; j < 4; ++j){
        int n = n0 + tx*4 + j;
        float a0 = acc[0][j], a1 = acc[1][j], a2 = acc[2][j], a3 = acc[3][j];
        avg_o[g_out*C_ + n] = f2b(0.25f*(a0+a1+a2+a3));
        max_o[g_out*C_ + n] = f2b(fmaxf(fmaxf(a0,a1), fmaxf(a2,a3)));
    }
}

// ---------------------------------------------------------------- S = (Q @ K^T) * SCALE  per batch
__global__ __launch_bounds__(256) void k_gemm_scores(const bf16* __restrict__ Q,
                                                     const bf16* __restrict__ K,
                                                     float* __restrict__ S){
    int bb = blockIdx.z;
    const bf16* Qb = Q + (size_t)bb*N_*C_;
    const bf16* Kb = K + (size_t)bb*N_*C_;
    float* Sb = S + (size_t)bb*N_*N_;
    __shared__ float As[TM][TK+1];
    __shared__ float Bs[TN][TK+1];
    int tid = threadIdx.x, tx = tid & 15, ty = tid >> 4;
    int m0 = blockIdx.y*TM, n0 = blockIdx.x*TN;
    float acc[4][4] = {};
    for (int k0 = 0; k0 < C_; k0 += TK){
        for (int e = tid; e < TM*TK; e += 256){
            int kk = e & 31, r = e >> 5;
            As[r][kk] = b2f(Qb[(m0 + r)*C_ + k0 + kk]);
        }
        for (int e = tid; e < TN*TK; e += 256){
            int kk = e & 31, r = e >> 5;
            Bs[r][kk] = b2f(Kb[(n0 + r)*C_ + k0 + kk]);
        }
        __syncthreads();
        #pragma unroll
        for (int kk = 0; kk < TK; ++kk){
            float a[4], b[4];
            #pragma unroll
            for (int i = 0; i < 4; ++i) a[i] = As[ty*4+i][kk];
            #pragma unroll
            for (int j = 0; j < 4; ++j) b[j] = Bs[tx*4+j][kk];
            #pragma unroll
            for (int i = 0; i < 4; ++i)
                #pragma unroll
                for (int j = 0; j < 4; ++j) acc[i][j] += a[i]*b[j];
        }
        __syncthreads();
    }
    #pragma unroll
    for (int i = 0; i < 4; ++i){
        int m = m0 + ty*4 + i;
        #pragma unroll
        for (int j = 0; j < 4; ++j)
            Sb[m*N_ + n0 + tx*4 + j] = acc[i][j]*SCALE_;
    }
}

// ---------------------------------------------------------------- row softmax over 1024, in place
__global__ __launch_bounds__(256) void k_softmax(float* __restrict__ S){
    float* p = S + (size_t)blockIdx.x*N_;
    __shared__ float red[256];
    int t = threadIdx.x;
    float v[4], m = -1e30f;
    #pragma unroll
    for (int i = 0; i < 4; ++i){ v[i] = p[i*256 + t]; m = fmaxf(m, v[i]); }
    red[t] = m; __syncthreads();
    for (int s = 128; s > 0; s >>= 1){ if (t < s) red[t] = fmaxf(red[t], red[t+s]); __syncthreads(); }
    m = red[0]; __syncthreads();
    float sum = 0.f;
    #pragma unroll
    for (int i = 0; i < 4; ++i){ v[i] = expf(v[i] - m); sum += v[i]; }
    red[t] = sum; __syncthreads();
    for (int s = 128; s > 0; s >>= 1){ if (t < s) red[t] += red[t+s]; __syncthreads(); }
    float inv = 1.f / red[0];
    #pragma unroll
    for (int i = 0; i < 4; ++i) p[i*256 + t] = v[i]*inv;
}

// ---------------------------------------------------------------- O^T = (P @ V)^T  per batch, bf16 out
// mode 1: out = beta*avgT + (1-beta)*acc  (combine for x_prev)
__global__ __launch_bounds__(256) void k_gemm_pv(const float* __restrict__ P,
                                                 const bf16* __restrict__ V,
                                                 bf16* __restrict__ outT,
                                                 const bf16* __restrict__ avgT,
                                                 const float* __restrict__ beta_p,
                                                 int mode){
    int bb = blockIdx.z;
    const float* Pb = P + (size_t)bb*N_*N_;
    const bf16*  Vb = V + (size_t)bb*N_*C_;
    __shared__ float As[TM][TK+1];
    __shared__ float Bs[TN][TK+1];
    int tid = threadIdx.x, tx = tid & 15, ty = tid >> 4;
    int m0 = blockIdx.y*TM, n0 = blockIdx.x*TN;
    float acc[4][4] = {};
    for (int k0 = 0; k0 < N_; k0 += TK){
        for (int e = tid; e < TM*TK; e += 256){
            int kk = e & 31, r = e >> 5;
            As[r][kk] = Pb[(m0 + r)*N_ + k0 + kk];
        }
        for (int e = tid; e < TN*TK; e += 256){   // V is [K=1024 tokens][N=512 ch]
            int col = e & 63, kk = e >> 6;
            Bs[col][kk] = b2f(Vb[(k0 + kk)*C_ + n0 + col]);
        }
        __syncthreads();
        #pragma unroll
        for (int kk = 0; kk < TK; ++kk){
            float a[4], b[4];
            #pragma unroll
            for (int i = 0; i < 4; ++i) a[i] = As[ty*4+i][kk];
            #pragma unroll
            for (int j = 0; j < 4; ++j) b[j] = Bs[tx*4+j][kk];
            #pragma unroll
            for (int i = 0; i < 4; ++i)
                #pragma unroll
                for (int j = 0; j < 4; ++j) acc[i][j] += a[i]*b[j];
        }
        __syncthreads();
    }
    float bet = (mode == 1) ? beta_p[0] : 0.f;
    #pragma unroll
    for (int i = 0; i < 4; ++i){
        int m = m0 + ty*4 + i;           // token
        #pragma unroll
        for (int j = 0; j < 4; ++j){
            int n = n0 + tx*4 + j;       // channel
            size_t dst = ((size_t)bb*C_ + n)*N_ + m;
            float val = acc[i][j];
            if (mode == 1) val = bet*b2f(avgT[dst]) + (1.f - bet)*val;
            outT[dst] = f2b(val);
        }
    }
}

// ---------------------------------------------------------------- fuse GEMM: cat(x_now,x_prev) @ fuse_w + fuse_b
// cat row (b,h,w): contiguous slice of the transposed attention outputs (torch reshape scramble)
__global__ __launch_bounds__(256) void k_gemm_fuse(const bf16* __restrict__ nowT,
                                                   const bf16* __restrict__ prevT,
                                                   const float* __restrict__ Wf,
                                                   const float* __restrict__ fb,
                                                   float* __restrict__ fusx){
    __shared__ float As[TM][TK+1];
    __shared__ float Bs[TN][TK+1];
    int tid = threadIdx.x, tx = tid & 15, ty = tid >> 4;
    int m0 = blockIdx.y*TM, n0 = blockIdx.x*TN;
    float acc[4][4] = {};
    for (int k0 = 0; k0 < 2*C_; k0 += TK){
        const bf16* src = (k0 < C_) ? nowT : prevT;
        for (int e = tid; e < TM*TK; e += 256){
            int kk = e & 31, r = e >> 5;
            int m = m0 + r;
            int b = m >> 10, rem = m & 1023, h = rem >> 5, w = rem & 31;
            int c_o = h*16 + (w >> 1);
            int base = (b*C_ + c_o)*N_ + ((w & 1) << 9);
            As[r][kk] = b2f(src[base + (k0 & (C_-1)) + kk]);
        }
        for (int e = tid; e < TN*TK; e += 256){   // fuse_w [K=1024][N=512]
            int col = e & 63, kk = e >> 6;
            Bs[col][kk] = Wf[(k0 + kk)*C_ + n0 + col];
        }
        __syncthreads();
        #pragma unroll
        for (int kk = 0; kk < TK; ++kk){
            float a[4], b[4];
            #pragma unroll
            for (int i = 0; i < 4; ++i) a[i] = As[ty*4+i][kk];
            #pragma unroll
            for (int j = 0; j < 4; ++j) b[j] = Bs[tx*4+j][kk];
            #pragma unroll
            for (int i = 0; i < 4; ++i)
                #pragma unroll
                for (int j = 0; j < 4; ++j) acc[i][j] += a[i]*b[j];
        }
        __syncthreads();
    }
    #pragma unroll
    for (int i = 0; i < 4; ++i){
        int m = m0 + ty*4 + i;
        #pragma unroll
        for (int j = 0; j < 4; ++j){
            int n = n0 + tx*4 + j;
            fusx[m*C_ + n] = acc[i][j] + fb[n];
        }
    }
}

// ---------------------------------------------------------------- per-channel sum/sumsq over [16384, 512]
__global__ __launch_bounds__(256) void k_stats(const float* __restrict__ in,
                                               float* __restrict__ sum,
                                               float* __restrict__ sumsq){
    int t = threadIdx.x, c0 = t*2, r0 = blockIdx.x*32;
    float s0=0, s1=0, q0=0, q1=0;
    for (int r = 0; r < 32; ++r){
        float2 v = *reinterpret_cast<const float2*>(in + (size_t)(r0+r)*C_ + c0);
        s0 += v.x; q0 += v.x*v.x; s1 += v.y; q1 += v.y*v.y;
    }
    atomicAdd(&sum[c0],   s0); atomicAdd(&sum[c0+1],   s1);
    atomicAdd(&sumsq[c0], q0); atomicAdd(&sumsq[c0+1], q1);
}

// ---------------------------------------------------------------- x2 = x + gamma*relu(BN1(fusx))
__global__ __launch_bounds__(256) void k_apply1(const float* __restrict__ fusx,
                                                const float* __restrict__ x,
                                                const float* __restrict__ sum,
                                                const float* __restrict__ sumsq,
                                                const float* __restrict__ g,
                                                const float* __restrict__ bb,
                                                const float* __restrict__ gamma,
                                                float* __restrict__ x2){
    int idx = blockIdx.x*256 + threadIdx.x;
    int c = idx & (C_-1);
    float mean = sum[c]*(1.f/NTOK);
    float var  = sumsq[c]*(1.f/NTOK) - mean*mean;
    float t = (fusx[idx] - mean)*rsqrtf(var + EPS_)*g[c] + bb[c];
    x2[idx] = x[idx] + gamma[0]*fmaxf(t, 0.f);
}

// ---------------------------------------------------------------- 3x3 SAME conv, NHWC x HWIO, fp32
__global__ __launch_bounds__(256) void k_conv(const float* __restrict__ X2,
                                              const float* __restrict__ Wc,
                                              const float* __restrict__ bias,
                                              float* __restrict__ Y){
    __shared__ float Xs[3][34][33];
    int tid = threadIdx.x;
    int oc_l = tid & 63, wq = tid >> 6;
    int oc = blockIdx.x*64 + oc_l;
    int h = blockIdx.y, b = blockIdx.z;
    int w0 = wq*8;
    float acc[8] = {};
    for (int ic0 = 0; ic0 < C_; ic0 += 32){
        for (int e = tid; e < 3*34*32; e += 256){
            int ic = e & 31, rest = e >> 5;
            int wi = rest % 34, dh = rest / 34;
            int hs = h + dh - 1, ws = wi - 1;
            float v = 0.f;
            if (hs >= 0 && hs < 32 && ws >= 0 && ws < 32)
                v = X2[((b*32 + hs)*32 + ws)*C_ + ic0 + ic];
            Xs[dh][wi][ic] = v;
        }
        __syncthreads();
        for (int dh = 0; dh < 3; ++dh){
            for (int ic = 0; ic < 32; ++ic){
                float xv[10];
                #pragma unroll
                for (int t = 0; t < 10; ++t) xv[t] = Xs[dh][w0 + t][ic];
                float wt0 = Wc[((dh*3+0)*C_ + ic0+ic)*C_ + oc];
                float wt1 = Wc[((dh*3+1)*C_ + ic0+ic)*C_ + oc];
                float wt2 = Wc[((dh*3+2)*C_ + ic0+ic)*C_ + oc];
                #pragma unroll
                for (int j = 0; j < 8; ++j)
                    acc[j] += xv[j]*wt0 + xv[j+1]*wt1 + xv[j+2]*wt2;
            }
        }
        __syncthreads();
    }
    float bz = bias[oc];
    #pragma unroll
    for (int j = 0; j < 8; ++j)
        Y[((b*32 + h)*32 + w0 + j)*C_ + oc] = acc[j] + bz;
}

// ---------------------------------------------------------------- out = relu(BN2(y)) in place
__global__ __launch_bounds__(256) void k_apply2(float* __restrict__ Y,
                                                const float* __restrict__ sum,
                                                const float* __restrict__ sumsq,
                                                const float* __restrict__ g,
                                                const float* __restrict__ bb){
    int idx = blockIdx.x*256 + threadIdx.x;
    int c = idx & (C_-1);
    float mean = sum[c]*(1.f/NTOK);
    float var  = sumsq[c]*(1.f/NTOK) - mean*mean;
    float t = (Y[idx] - mean)*rsqrtf(var + EPS_)*g[c] + bb[c];
    Y[idx] = fmaxf(t, 0.f);
}

extern "C" void kernel_launch(void* const* d_in, const int* in_sizes, int n_in,
                              void* d_out, int out_size, void* d_ws, size_t ws_size,
                              hipStream_t stream){
    const float* x      = (const float*)d_in[0];
    const float* prevx  = (const float*)d_in[1];
    const float* w_prev = (const float*)d_in[2];
    const float* w_qkv  = (const float*)d_in[3];
    const float* fuse_w = (const float*)d_in[4];
    const float* fuse_b = (const float*)d_in[5];
    const float* bn1_g  = (const float*)d_in[6];
    const float* bn1_b  = (const float*)d_in[7];
    const float* out_w  = (const float*)d_in[8];
    const float* out_b  = (const float*)d_in[9];
    const float* bn2_g  = (const float*)d_in[10];
    const float* bn2_b  = (const float*)d_in[11];
    const float* gamma  = (const float*)d_in[12];
    const float* beta   = (const float*)d_in[13];
    float* out = (float*)d_out;

    char* ws = (char*)d_ws;
    const size_t SZB = 16777216;                 // one [B,N,C] bf16 tensor
    bf16* qkv   = (bf16*)(ws);
    bf16* avgk  = (bf16*)(ws + 1*SZB);
    bf16* maxk  = (bf16*)(ws + 2*SZB);
    bf16* nowT  = (bf16*)(ws + 3*SZB);
    bf16* avgT  = (bf16*)(ws + 4*SZB);
    bf16* prevT = (bf16*)(ws + 5*SZB);
    float* S    = (float*)(ws + 6*SZB);          // 67,108,864 B
    float* fusx = S;                             // alias: used after attention is done
    float* x2   = (float*)(ws + 6*SZB + 33554432); // second half of S region
    float* st   = (float*)(ws + 6*SZB + 67108864); // 2048 floats
    float* s1sum = st, *s1sq = st + 512, *s2sum = st + 1024, *s2sq = st + 1536;

    dim3 blk(256);
    k_zero<<<8, blk, 0, stream>>>(st, 2048);
    k_gemm_qkv<<<dim3(8, 256), blk, 0, stream>>>(x, w_qkv, qkv);
    k_gemm_prev_pool<<<dim3(8, 1024), blk, 0, stream>>>(prevx, w_prev, avgk, maxk);
    // avg attention
    k_gemm_scores<<<dim3(16,16,16), blk, 0, stream>>>(qkv, avgk, S);
    k_softmax<<<16384, blk, 0, stream>>>(S);
    k_gemm_pv<<<dim3(8,16,16), blk, 0, stream>>>(S, avgk, avgT, nullptr, nullptr, 0);
    // max attention (+ combine into x_prev^T)
    k_gemm_scores<<<dim3(16,16,16), blk, 0, stream>>>(qkv, maxk, S);
    k_softmax<<<16384, blk, 0, stream>>>(S);
    k_gemm_pv<<<dim3(8,16,16), blk, 0, stream>>>(S, maxk, prevT, avgT, beta, 1);
    // self attention
    k_gemm_scores<<<dim3(16,16,16), blk, 0, stream>>>(qkv, qkv, S);
    k_softmax<<<16384, blk, 0, stream>>>(S);
    k_gemm_pv<<<dim3(8,16,16), blk, 0, stream>>>(S, qkv, nowT, nullptr, nullptr, 0);
    // fuse + BN1 + residual
    k_gemm_fuse<<<dim3(8, 256), blk, 0, stream>>>(nowT, prevT, fuse_w, fuse_b, fusx);
    k_stats<<<512, blk, 0, stream>>>(fusx, s1sum, s1sq);
    k_apply1<<<32768, blk, 0, stream>>>(fusx, x, s1sum, s1sq, bn1_g, bn1_b, gamma, x2);
    // conv + BN2
    k_conv<<<dim3(8, 32, 16), blk, 0, stream>>>(x2, out_w, out_b, out);
    k_stats<<<512, blk, 0, stream>>>(out, s2sum, s2sq);
    k_apply2<<<32768, blk, 0, stream>>>(out, s2sum, s2sq, bn2_g, bn2_b);
}

// Round 2
// 664.393 us; speedup vs baseline: 8.6091x; 8.6091x over previous
//
#include <hip/hip_runtime.h>
#include <hip/hip_bf16.h>

#define B_   16
#define C_   512
#define N_   1024
#define NTOK 16384
#define SCALE_ 0.17677669529663687f
#define EPS_ 1e-5f

typedef __attribute__((ext_vector_type(8))) short bf16x8;
typedef __attribute__((ext_vector_type(4))) float f32x4;
typedef __attribute__((ext_vector_type(4))) short sh4;

#define GLOBAL_AS __attribute__((address_space(1)))
#define LDS_AS    __attribute__((address_space(3)))

__device__ __forceinline__ short f2bs(float v){
    __hip_bfloat16 h = __float2bfloat16(v);
    return *reinterpret_cast<short*>(&h);
}
__device__ __forceinline__ float bs2f(short s){
    __hip_bfloat16 h = *reinterpret_cast<__hip_bfloat16*>(&s);
    return __bfloat162float(h);
}
__device__ __forceinline__ void gload16(const void* g, void* l){
    __builtin_amdgcn_global_load_lds((const GLOBAL_AS unsigned int*)g,
                                     (LDS_AS unsigned int*)l, 16, 0, 0);
}

enum { AG_ROW = 0, AG_POOL = 1, AG_FUSE = 2, AG_CONV = 3 };
enum { EP_QKV = 0, EP_POOL = 1, EP_SCORES = 2, EP_PV0 = 3, EP_PV1 = 4, EP_BIAS_F32 = 5 };

// ------------------------------------------------------------------ utility kernels
__global__ __launch_bounds__(256) void k_zero(float* p, int n){
    int i = blockIdx.x*256 + threadIdx.x;
    if (i < n) p[i] = 0.f;
}

__global__ __launch_bounds__(256) void k_cast(const float* __restrict__ s, short* __restrict__ d, int n){
    int i = (blockIdx.x*256 + threadIdx.x)*4;
    if (i >= n) return;
    float4 v = *reinterpret_cast<const float4*>(s + i);
    sh4 o; o[0]=f2bs(v.x); o[1]=f2bs(v.y); o[2]=f2bs(v.z); o[3]=f2bs(v.w);
    *reinterpret_cast<sh4*>(d + i) = o;
}

// transpose-cast: src fp32 [R][Cc] -> dst bf16 [Cc][R]
__global__ __launch_bounds__(256) void k_tcast(const float* __restrict__ src, short* __restrict__ dst,
                                               int R, int Cc){
    __shared__ float t[32][33];
    int bx = blockIdx.x*32, by = blockIdx.y*32;
    int tx = threadIdx.x & 31, ty = threadIdx.x >> 5;
    #pragma unroll
    for (int i = 0; i < 32; i += 8)
        t[ty+i][tx] = src[(size_t)(by+ty+i)*Cc + bx+tx];
    __syncthreads();
    #pragma unroll
    for (int i = 0; i < 32; i += 8)
        dst[(size_t)(bx+ty+i)*R + by+tx] = f2bs(t[tx][ty+i]);
}

// ------------------------------------------------------------------ MFMA GEMM template
// C[m][n] = sum_k A[m][k]*Bt[n][k]; 128x128 tile, BK=32, 4 waves (2x2 of 64x64), 4x4 16x16 frags
template<int AM, int EP, int MT, int NT, int KT, long ASTR, long BSTR>
__global__ __launch_bounds__(256) void k_mm(const short* __restrict__ A,
                                            const short* __restrict__ Bt,
                                            const short* __restrict__ A2,
                                            const short* __restrict__ XT,
                                            const float* __restrict__ sc0,
                                            void* __restrict__ O0,
                                            void* __restrict__ O1,
                                            void* __restrict__ O2,
                                            void* __restrict__ O3){
    __shared__ short Asm[128*32];
    __shared__ short Bsm[128*32];
    const int tid = threadIdx.x, wave = tid >> 6, lane = tid & 63;
    const int bz = blockIdx.z;
    const int m0 = blockIdx.y*128, n0 = blockIdx.x*128;
    const short* Ab = A + (size_t)bz*ASTR;
    const short* Bb = Bt + (size_t)bz*BSTR;

    f32x4 acc[4][4];
    #pragma unroll
    for (int i = 0; i < 4; ++i)
        #pragma unroll
        for (int j = 0; j < 4; ++j)
            acc[i][j] = (f32x4){0.f,0.f,0.f,0.f};

    const int wm = (wave >> 1)*64, wn = (wave & 1)*64;
    const int lrow = lane & 15, lk = (lane >> 4)*8;

    for (int k0 = 0; k0 < KT; k0 += 32){
        #pragma unroll
        for (int is = 0; is < 2; ++is){
            int fl = is*256 + tid;           // 16B chunk index within 128x32 tile
            int r = fl >> 2, ccol = (fl & 3)*8;
            const short* ga;
            if constexpr (AM == AG_ROW){
                ga = Ab + (size_t)(m0 + r)*KT + (k0 + ccol);
            } else if constexpr (AM == AG_POOL){
                int m = m0 + r;
                int b = m >> 12, rem = m & 4095, g = rem >> 2, q = rem & 3;
                int srow = (b*64 + (g>>5)*2 + (q>>1))*64 + (g&31)*2 + (q&1);
                ga = Ab + (size_t)srow*256 + (k0 + ccol);
            } else if constexpr (AM == AG_FUSE){
                int m = m0 + r;
                int b = m >> 10, rem = m & 1023, h = rem >> 5, w = rem & 31;
                int kk = k0 + ccol;
                const short* src = (kk < 512) ? A : A2;
                ga = src + ((size_t)(b*512 + h*16 + (w>>1))*1024 + ((w&1)<<9) + (kk & 511));
            } else { // AG_CONV: implicit 3x3 gemm from x2q [16,32,32,512]
                int m = m0 + r;
                int b = m >> 10, rem = m & 1023, h = rem >> 5, w = rem & 31;
                int kk = k0 + ccol;
                int tap = kk >> 9, ic = kk & 511;
                int dh = tap/3 - 1, dw = tap - (tap/3)*3 - 1;
                int hs = h + dh, wd = w + dw;
                if (hs >= 0 && hs < 32 && wd >= 0 && wd < 32)
                    ga = A + ((size_t)((b*32 + hs)*32 + wd)*512 + ic);
                else
                    ga = A2;                 // zero page
            }
            gload16(ga, &Asm[(is*4 + wave)*512]);
            const short* gb = Bb + (size_t)(n0 + r)*KT + (k0 + ccol);
            gload16(gb, &Bsm[(is*4 + wave)*512]);
        }
        __syncthreads();
        bf16x8 af[4], bfr[4];
        #pragma unroll
        for (int mi = 0; mi < 4; ++mi)
            af[mi] = *(const bf16x8*)&Asm[(wm + mi*16 + lrow)*32 + lk];
        #pragma unroll
        for (int nj = 0; nj < 4; ++nj)
            bfr[nj] = *(const bf16x8*)&Bsm[(wn + nj*16 + lrow)*32 + lk];
        #pragma unroll
        for (int mi = 0; mi < 4; ++mi)
            #pragma unroll
            for (int nj = 0; nj < 4; ++nj)
                acc[mi][nj] = __builtin_amdgcn_mfma_f32_16x16x32_bf16(af[mi], bfr[nj], acc[mi][nj], 0, 0, 0);
        __syncthreads();
    }

    // ---------------- epilogue: C/D layout col=lane&15, row=(lane>>4)*4+reg
    float bet = 0.f;
    if constexpr (EP == EP_PV1) bet = sc0[0];
    const int lg = lane >> 4;
    #pragma unroll
    for (int mi = 0; mi < 4; ++mi)
        #pragma unroll
        for (int nj = 0; nj < 4; ++nj){
            int c  = n0 + wn + nj*16 + lrow;
            int r0 = m0 + wm + mi*16 + lg*4;
            f32x4 v = acc[mi][nj];
            if constexpr (EP == EP_QKV){
                sh4 t4;
                #pragma unroll
                for (int rg = 0; rg < 4; ++rg){
                    short s = f2bs(v[rg]);
                    ((short*)O0)[(size_t)(r0+rg)*NT + c] = s;
                    t4[rg] = s;
                }
                int b = r0 >> 10, t = r0 & 1023;
                *reinterpret_cast<sh4*>((short*)O1 + ((size_t)(b*512 + c))*1024 + t) = t4;
            } else if constexpr (EP == EP_POOL){
                float av = 0.25f*(v[0]+v[1]+v[2]+v[3]);
                float mx = fmaxf(fmaxf(v[0],v[1]), fmaxf(v[2],v[3]));
                int g = r0 >> 2;
                int b = g >> 10, t = g & 1023;
                ((short*)O0)[(size_t)g*512 + c] = f2bs(av);
                ((short*)O2)[(size_t)g*512 + c] = f2bs(mx);
                ((short*)O1)[((size_t)(b*512 + c))*1024 + t] = f2bs(av);
                ((short*)O3)[((size_t)(b*512 + c))*1024 + t] = f2bs(mx);
            } else if constexpr (EP == EP_SCORES){
                float* O = (float*)O0 + (size_t)bz*MT*NT;
                #pragma unroll
                for (int rg = 0; rg < 4; ++rg)
                    O[(size_t)(r0+rg)*NT + c] = v[rg]*SCALE_;
            } else if constexpr (EP == EP_PV0 || EP == EP_PV1){
                short* O = (short*)O0 + (size_t)bz*MT*NT;
                #pragma unroll
                for (int rg = 0; rg < 4; ++rg){
                    size_t dst = (size_t)(r0+rg)*NT + c;
                    float val = v[rg];
                    if constexpr (EP == EP_PV1)
                        val = bet*bs2f(XT[(size_t)bz*MT*NT + dst]) + (1.f - bet)*val;
                    O[dst] = f2bs(val);
                }
            } else { // EP_BIAS_F32
                float bias = sc0[c];
                #pragma unroll
                for (int rg = 0; rg < 4; ++rg)
                    ((float*)O0)[(size_t)(r0+rg)*NT + c] = v[rg] + bias;
            }
        }
}

// ------------------------------------------------------------------ softmax (fp32 in, bf16 out)
__global__ __launch_bounds__(256) void k_softmax(const float* __restrict__ S, short* __restrict__ P){
    const float* p = S + (size_t)blockIdx.x*N_;
    short* q = P + (size_t)blockIdx.x*N_;
    __shared__ float red[256];
    int t = threadIdx.x;
    float v[4], m = -1e30f;
    #pragma unroll
    for (int i = 0; i < 4; ++i){ v[i] = p[i*256 + t]; m = fmaxf(m, v[i]); }
    red[t] = m; __syncthreads();
    for (int s = 128; s > 0; s >>= 1){ if (t < s) red[t] = fmaxf(red[t], red[t+s]); __syncthreads(); }
    m = red[0]; __syncthreads();
    float sum = 0.f;
    #pragma unroll
    for (int i = 0; i < 4; ++i){ v[i] = expf(v[i] - m); sum += v[i]; }
    red[t] = sum; __syncthreads();
    for (int s = 128; s > 0; s >>= 1){ if (t < s) red[t] += red[t+s]; __syncthreads(); }
    float inv = 1.f / red[0];
    #pragma unroll
    for (int i = 0; i < 4; ++i) q[i*256 + t] = f2bs(v[i]*inv);
}

// ------------------------------------------------------------------ BN stats / apply
__global__ __launch_bounds__(256) void k_stats(const float* __restrict__ in,
                                               float* __restrict__ sum, float* __restrict__ sumsq){
    int t = threadIdx.x, c0 = t*2, r0 = blockIdx.x*32;
    float s0=0, s1=0, q0=0, q1=0;
    for (int r = 0; r < 32; ++r){
        float2 v = *reinterpret_cast<const float2*>(in + (size_t)(r0+r)*C_ + c0);
        s0 += v.x; q0 += v.x*v.x; s1 += v.y; q1 += v.y*v.y;
    }
    atomicAdd(&sum[c0],   s0); atomicAdd(&sum[c0+1],   s1);
    atomicAdd(&sumsq[c0], q0); atomicAdd(&sumsq[c0+1], q1);
}

__global__ __launch_bounds__(256) void k_apply1(const float* __restrict__ fusx,
                                                const float* __restrict__ x,
                                                const float* __restrict__ sum,
                                                const float* __restrict__ sumsq,
                                                const float* __restrict__ g,
                                                const float* __restrict__ bb,
                                                const float* __restrict__ gamma,
                                                short* __restrict__ x2q){
    int idx = blockIdx.x*256 + threadIdx.x;
    int c = idx & (C_-1);
    float mean = sum[c]*(1.f/NTOK);
    float var  = sumsq[c]*(1.f/NTOK) - mean*mean;
    float t = (fusx[idx] - mean)*rsqrtf(var + EPS_)*g[c] + bb[c];
    x2q[idx] = f2bs(x[idx] + gamma[0]*fmaxf(t, 0.f));
}

__global__ __launch_bounds__(256) void k_apply2(float* __restrict__ Y,
                                                const float* __restrict__ sum,
                                                const float* __restrict__ sumsq,
                                                const float* __restrict__ g,
                                                const float* __restrict__ bb){
    int idx = blockIdx.x*256 + threadIdx.x;
    int c = idx & (C_-1);
    float mean = sum[c]*(1.f/NTOK);
    float var  = sumsq[c]*(1.f/NTOK) - mean*mean;
    float t = (Y[idx] - mean)*rsqrtf(var + EPS_)*g[c] + bb[c];
    Y[idx] = fmaxf(t, 0.f);
}

// ------------------------------------------------------------------ launch
extern "C" void kernel_launch(void* const* d_in, const int* in_sizes, int n_in,
                              void* d_out, int out_size, void* d_ws, size_t ws_size,
                              hipStream_t stream){
    const float* x      = (const float*)d_in[0];
    const float* prevx  = (const float*)d_in[1];
    const float* w_prev = (const float*)d_in[2];
    const float* w_qkv  = (const float*)d_in[3];
    const float* fuse_w = (const float*)d_in[4];
    const float* fuse_b = (const float*)d_in[5];
    const float* bn1_g  = (const float*)d_in[6];
    const float* bn1_b  = (const float*)d_in[7];
    const float* out_w  = (const float*)d_in[8];
    const float* out_b  = (const float*)d_in[9];
    const float* bn2_g  = (const float*)d_in[10];
    const float* bn2_b  = (const float*)d_in[11];
    const float* gamma  = (const float*)d_in[12];
    const float* beta   = (const float*)d_in[13];
    float* out = (float*)d_out;

    char* ws8 = (char*)d_ws;
    float* S    = (float*)(ws8 + 0);             // 67.1 MB
    short* pxq  = (short*)(ws8 + 0);             // alias (dead before scores-avg)
    short* Pq   = (short*)(ws8 + 67108864);      // 33.6 MB
    short* xq   = (short*)(ws8 + 100663296);     // 16.8 MB
    short* avgk = xq;                            // alias after qkv GEMM
    short* qkv  = (short*)(ws8 + 117440512);
    short* x2q  = qkv;                           // alias after scores-max
    short* qkvT = (short*)(ws8 + 134217728);
    short* avgkT= qkvT;                          // alias after PV-self
    short* prevT= qkvT;                          // alias after PV-avg
    short* nowT = (short*)(ws8 + 150994944);
    short* maxk = (short*)(ws8 + 167772160);
    short* maxkT= (short*)(ws8 + 184549376);
    float* fusx = (float*)(ws8 + 167772160);     // alias maxk+maxkT after PV-max
    short* avgT = (short*)(ws8 + 201326592);
    short* wqT  = (short*)(ws8 + 218103808);
    short* wpT  = (short*)(ws8 + 218628096);
    short* wfT  = (short*)(ws8 + 218890240);
    short* wcT  = (short*)(ws8 + 219938816);
    float* st   = (float*)(ws8 + 224657408);     // 2048 stats + 256 zero page floats
    short* zpg  = (short*)(ws8 + 224665600);
    float *s1sum = st, *s1sq = st + 512, *s2sum = st + 1024, *s2sq = st + 1536;

    dim3 blk(256);
    k_zero<<<9, blk, 0, stream>>>(st, 2304);
    // casts / weight transposes
    k_cast<<<8192, blk, 0, stream>>>(x, xq, 8388608);
    k_cast<<<256,  blk, 0, stream>>>(w_qkv, wqT, 262144);
    k_cast<<<128,  blk, 0, stream>>>(w_prev, wpT, 131072);
    k_tcast<<<dim3(16, 32),  blk, 0, stream>>>(fuse_w, wfT, 1024, 512);
    k_tcast<<<dim3(16, 144), blk, 0, stream>>>(out_w, wcT, 4608, 512);

    // qkv = x @ w_qkv^T  (row-major + transposed)
    k_mm<AG_ROW, EP_QKV, 16384, 512, 512, 0L, 0L>
        <<<dim3(4,128,1), blk, 0, stream>>>(xq, wqT, nullptr, nullptr, nullptr,
                                            qkv, qkvT, nullptr, nullptr);
    // self attention
    k_mm<AG_ROW, EP_SCORES, 1024, 1024, 512, 524288L, 524288L>
        <<<dim3(8,8,16), blk, 0, stream>>>(qkv, qkv, nullptr, nullptr, nullptr,
                                           S, nullptr, nullptr, nullptr);
    k_softmax<<<16384, blk, 0, stream>>>(S, Pq);
    k_mm<AG_ROW, EP_PV0, 512, 1024, 1024, 524288L, 1048576L>
        <<<dim3(8,4,16), blk, 0, stream>>>(qkvT, Pq, nullptr, nullptr, nullptr,
                                           nowT, nullptr, nullptr, nullptr);
    // prev qkv + fused 2x2 pooling
    k_cast<<<16384, blk, 0, stream>>>(prevx, pxq, 16777216);
    k_mm<AG_POOL, EP_POOL, 65536, 512, 256, 0L, 0L>
        <<<dim3(4,512,1), blk, 0, stream>>>(pxq, wpT, nullptr, nullptr, nullptr,
                                            avgk, avgkT, maxk, maxkT);
    // avg attention
    k_mm<AG_ROW, EP_SCORES, 1024, 1024, 512, 524288L, 524288L>
        <<<dim3(8,8,16), blk, 0, stream>>>(qkv, avgk, nullptr, nullptr, nullptr,
                                           S, nullptr, nullptr, nullptr);
    k_softmax<<<16384, blk, 0, stream>>>(S, Pq);
    k_mm<AG_ROW, EP_PV0, 512, 1024, 1024, 524288L, 1048576L>
        <<<dim3(8,4,16), blk, 0, stream>>>(avgkT, Pq, nullptr, nullptr, nullptr,
                                           avgT, nullptr, nullptr, nullptr);
    // max attention + beta-combine -> prevT
    k_mm<AG_ROW, EP_SCORES, 1024, 1024, 512, 524288L, 524288L>
        <<<dim3(8,8,16), blk, 0, stream>>>(qkv, maxk, nullptr, nullptr, nullptr,
                                           S, nullptr, nullptr, nullptr);
    k_softmax<<<16384, blk, 0, stream>>>(S, Pq);
    k_mm<AG_ROW, EP_PV1, 512, 1024, 1024, 524288L, 1048576L>
        <<<dim3(8,4,16), blk, 0, stream>>>(maxkT, Pq, nullptr, avgT, beta,
                                           prevT, nullptr, nullptr, nullptr);
    // fuse 1x1 + BN1 + residual
    k_mm<AG_FUSE, EP_BIAS_F32, 16384, 512, 1024, 0L, 0L>
        <<<dim3(4,128,1), blk, 0, stream>>>(nowT, wfT, prevT, nullptr, fuse_b,
                                            fusx, nullptr, nullptr, nullptr);
    k_stats<<<512, blk, 0, stream>>>(fusx, s1sum, s1sq);
    k_apply1<<<32768, blk, 0, stream>>>(fusx, x, s1sum, s1sq, bn1_g, bn1_b, gamma, x2q);
    // 3x3 conv (implicit GEMM) + BN2
    k_mm<AG_CONV, EP_BIAS_F32, 16384, 512, 4608, 0L, 0L>
        <<<dim3(4,128,1), blk, 0, stream>>>(x2q, wcT, zpg, nullptr, out_b,
                                            out, nullptr, nullptr, nullptr);
    k_stats<<<512, blk, 0, stream>>>(out, s2sum, s2sq);
    k_apply2<<<32768, blk, 0, stream>>>(out, s2sum, s2sq, bn2_g, bn2_b);
}

// Round 3
// 630.700 us; speedup vs baseline: 9.0690x; 1.0534x over previous
//
#include <hip/hip_runtime.h>
#include <hip/hip_bf16.h>

#define B_   16
#define C_   512
#define N_   1024
#define NTOK 16384
#define SCALE_ 0.17677669529663687f
#define EPS_ 1e-5f

typedef __attribute__((ext_vector_type(8))) short bf16x8;
typedef __attribute__((ext_vector_type(4))) float f32x4;
typedef __attribute__((ext_vector_type(4))) short sh4;

#define GLOBAL_AS __attribute__((address_space(1)))
#define LDS_AS    __attribute__((address_space(3)))

__device__ __forceinline__ short f2bs(float v){
    __hip_bfloat16 h = __float2bfloat16(v);
    return *reinterpret_cast<short*>(&h);
}
__device__ __forceinline__ float bs2f(short s){
    __hip_bfloat16 h = *reinterpret_cast<__hip_bfloat16*>(&s);
    return __bfloat162float(h);
}
__device__ __forceinline__ void gload16(const void* g, void* l){
    __builtin_amdgcn_global_load_lds((const GLOBAL_AS unsigned int*)g,
                                     (LDS_AS unsigned int*)l, 16, 0, 0);
}

enum { AG_ROW = 0, AG_POOL = 1, AG_FUSE = 2, AG_CONV = 3 };
enum { EP_QKV = 0, EP_POOL = 1, EP_SCORES = 2, EP_PV0 = 3, EP_PV1 = 4, EP_BIAS_F32 = 5 };
enum { ORD_INNER_N = 0, ORD_INNER_M = 1 };   // inner-n: consecutive blocks share A panel
                                             // inner-m: consecutive blocks share B panel

// ------------------------------------------------------------------ utility kernels
__global__ __launch_bounds__(256) void k_zero(float* p, int n){
    int i = blockIdx.x*256 + threadIdx.x;
    if (i < n) p[i] = 0.f;
}

__global__ __launch_bounds__(256) void k_cast(const float* __restrict__ s, short* __restrict__ d, int n){
    int i = (blockIdx.x*256 + threadIdx.x)*4;
    if (i >= n) return;
    float4 v = *reinterpret_cast<const float4*>(s + i);
    sh4 o; o[0]=f2bs(v.x); o[1]=f2bs(v.y); o[2]=f2bs(v.z); o[3]=f2bs(v.w);
    *reinterpret_cast<sh4*>(d + i) = o;
}

// transpose-cast: src fp32 [R][Cc] -> dst bf16 [Cc][R]
__global__ __launch_bounds__(256) void k_tcast(const float* __restrict__ src, short* __restrict__ dst,
                                               int R, int Cc){
    __shared__ float t[32][33];
    int bx = blockIdx.x*32, by = blockIdx.y*32;
    int tx = threadIdx.x & 31, ty = threadIdx.x >> 5;
    #pragma unroll
    for (int i = 0; i < 32; i += 8)
        t[ty+i][tx] = src[(size_t)(by+ty+i)*Cc + bx+tx];
    __syncthreads();
    #pragma unroll
    for (int i = 0; i < 32; i += 8)
        dst[(size_t)(bx+ty+i)*R + by+tx] = f2bs(t[tx][ty+i]);
}

// ------------------------------------------------------------------ MFMA GEMM template
// C[m][n] = sum_k A[m][k]*Bt[n][k]; 128x128 tile, BK=32, 4 waves (2x2 of 64x64), 4x4 16x16 frags
// 1-D grid, bijective XCD-chunked swizzle (8 XCDs), ORDER picks which panel stays L2-hot.
template<int AM, int EP, int ORDER, int NX, int NY, int NZ, int NT, int KT, long ASTR, long BSTR>
__global__ __launch_bounds__(256) void k_mm(const short* __restrict__ A,
                                            const short* __restrict__ Bt,
                                            const short* __restrict__ A2,
                                            const short* __restrict__ XT,
                                            const float* __restrict__ sc0,
                                            void* __restrict__ O0,
                                            void* __restrict__ O1,
                                            void* __restrict__ O2,
                                            void* __restrict__ O3){
    __shared__ short Asm[128*32];
    __shared__ short Bsm[128*32];
    const int tid = threadIdx.x, wave = tid >> 6, lane = tid & 63;

    // ---- chunked XCD swizzle (bijective, m204) ----
    constexpr int nwg = NX*NY*NZ;
    constexpr int q8 = nwg >> 3, r8 = nwg & 7;
    int orig = blockIdx.x;
    int xcd = orig & 7, idx8 = orig >> 3;
    int wg = (xcd < r8 ? xcd*(q8+1) : r8*(q8+1) + (xcd - r8)*q8) + idx8;
    int bz = wg / (NX*NY);
    int rem = wg - bz*(NX*NY);
    int nx, my;
    if constexpr (ORDER == ORD_INNER_N){ my = rem / NX; nx = rem - my*NX; }
    else                               { nx = rem / NY; my = rem - nx*NY; }

    const int m0 = my*128, n0 = nx*128;
    const short* Ab = A + (size_t)bz*ASTR;
    const short* Bb = Bt + (size_t)bz*BSTR;

    f32x4 acc[4][4];
    #pragma unroll
    for (int i = 0; i < 4; ++i)
        #pragma unroll
        for (int j = 0; j < 4; ++j)
            acc[i][j] = (f32x4){0.f,0.f,0.f,0.f};

    const int wm = (wave >> 1)*64, wn = (wave & 1)*64;
    const int lrow = lane & 15, lk = (lane >> 4)*8;

    for (int k0 = 0; k0 < KT; k0 += 32){
        #pragma unroll
        for (int is = 0; is < 2; ++is){
            int fl = is*256 + tid;           // 16B chunk index within 128x32 tile
            int r = fl >> 2, ccol = (fl & 3)*8;
            const short* ga;
            if constexpr (AM == AG_ROW){
                ga = Ab + (size_t)(m0 + r)*KT + (k0 + ccol);
            } else if constexpr (AM == AG_POOL){
                int m = m0 + r;
                int b = m >> 12, rem2 = m & 4095, g = rem2 >> 2, qd = rem2 & 3;
                int srow = (b*64 + (g>>5)*2 + (qd>>1))*64 + (g&31)*2 + (qd&1);
                ga = Ab + (size_t)srow*256 + (k0 + ccol);
            } else if constexpr (AM == AG_FUSE){
                int m = m0 + r;
                int b = m >> 10, rem2 = m & 1023, h = rem2 >> 5, w = rem2 & 31;
                int kk = k0 + ccol;
                const short* src = (kk < 512) ? A : A2;
                ga = src + ((size_t)(b*512 + h*16 + (w>>1))*1024 + ((w&1)<<9) + (kk & 511));
            } else { // AG_CONV: implicit 3x3 gemm from x2q [16,32,32,512]
                int m = m0 + r;
                int b = m >> 10, rem2 = m & 1023, h = rem2 >> 5, w = rem2 & 31;
                int kk = k0 + ccol;
                int tap = kk >> 9, ic = kk & 511;
                int dh = tap/3 - 1, dw = tap - (tap/3)*3 - 1;
                int hs = h + dh, wd = w + dw;
                if (hs >= 0 && hs < 32 && wd >= 0 && wd < 32)
                    ga = A + ((size_t)((b*32 + hs)*32 + wd)*512 + ic);
                else
                    ga = A2;                 // zero page
            }
            gload16(ga, &Asm[(is*4 + wave)*512]);
            const short* gb = Bb + (size_t)(n0 + r)*KT + (k0 + ccol);
            gload16(gb, &Bsm[(is*4 + wave)*512]);
        }
        __syncthreads();
        bf16x8 af[4], bfr[4];
        #pragma unroll
        for (int mi = 0; mi < 4; ++mi)
            af[mi] = *(const bf16x8*)&Asm[(wm + mi*16 + lrow)*32 + lk];
        #pragma unroll
        for (int nj = 0; nj < 4; ++nj)
            bfr[nj] = *(const bf16x8*)&Bsm[(wn + nj*16 + lrow)*32 + lk];
        #pragma unroll
        for (int mi = 0; mi < 4; ++mi)
            #pragma unroll
            for (int nj = 0; nj < 4; ++nj)
                acc[mi][nj] = __builtin_amdgcn_mfma_f32_16x16x32_bf16(af[mi], bfr[nj], acc[mi][nj], 0, 0, 0);
        __syncthreads();
    }

    // ---------------- epilogue: C/D layout col=lane&15, row=(lane>>4)*4+reg
    float bet = 0.f;
    if constexpr (EP == EP_PV1) bet = sc0[0];
    const int lg = lane >> 4;
    #pragma unroll
    for (int mi = 0; mi < 4; ++mi)
        #pragma unroll
        for (int nj = 0; nj < 4; ++nj){
            int c  = n0 + wn + nj*16 + lrow;
            int r0 = m0 + wm + mi*16 + lg*4;
            f32x4 v = acc[mi][nj];
            if constexpr (EP == EP_QKV){
                sh4 t4;
                #pragma unroll
                for (int rg = 0; rg < 4; ++rg){
                    short s = f2bs(v[rg]);
                    ((short*)O0)[(size_t)(r0+rg)*NT + c] = s;
                    t4[rg] = s;
                }
                int b = r0 >> 10, t = r0 & 1023;
                *reinterpret_cast<sh4*>((short*)O1 + ((size_t)(b*512 + c))*1024 + t) = t4;
            } else if constexpr (EP == EP_POOL){
                float av = 0.25f*(v[0]+v[1]+v[2]+v[3]);
                float mx = fmaxf(fmaxf(v[0],v[1]), fmaxf(v[2],v[3]));
                int g = r0 >> 2;
                int b = g >> 10, t = g & 1023;
                ((short*)O0)[(size_t)g*512 + c] = f2bs(av);
                ((short*)O2)[(size_t)g*512 + c] = f2bs(mx);
                ((short*)O1)[((size_t)(b*512 + c))*1024 + t] = f2bs(av);
                ((short*)O3)[((size_t)(b*512 + c))*1024 + t] = f2bs(mx);
            } else if constexpr (EP == EP_SCORES){
                float* O = (float*)O0 + (size_t)bz*(long)N_*NT;
                #pragma unroll
                for (int rg = 0; rg < 4; ++rg)
                    O[(size_t)(r0+rg)*NT + c] = v[rg]*SCALE_;
            } else if constexpr (EP == EP_PV0 || EP == EP_PV1){
                short* O = (short*)O0 + (size_t)bz*(long)C_*NT;
                #pragma unroll
                for (int rg = 0; rg < 4; ++rg){
                    size_t dst = (size_t)(r0+rg)*NT + c;
                    float val = v[rg];
                    if constexpr (EP == EP_PV1)
                        val = bet*bs2f(XT[(size_t)bz*(long)C_*NT + dst]) + (1.f - bet)*val;
                    O[dst] = f2bs(val);
                }
            } else { // EP_BIAS_F32
                float bias = sc0[c];
                #pragma unroll
                for (int rg = 0; rg < 4; ++rg)
                    ((float*)O0)[(size_t)(r0+rg)*NT + c] = v[rg] + bias;
            }
        }
}

// ------------------------------------------------------------------ softmax (fp32 in, bf16 out), vectorized
__global__ __launch_bounds__(256) void k_softmax(const float* __restrict__ S, short* __restrict__ P){
    const float4* p = reinterpret_cast<const float4*>(S + (size_t)blockIdx.x*N_);
    short* qp = P + (size_t)blockIdx.x*N_;
    __shared__ float red[8];
    int t = threadIdx.x, lane = t & 63, wv = t >> 6;
    float4 v = p[t];
    float m = fmaxf(fmaxf(v.x, v.y), fmaxf(v.z, v.w));
    #pragma unroll
    for (int o = 32; o > 0; o >>= 1) m = fmaxf(m, __shfl_xor(m, o));
    if (lane == 0) red[wv] = m;
    __syncthreads();
    m = fmaxf(fmaxf(red[0], red[1]), fmaxf(red[2], red[3]));
    float e0 = expf(v.x - m), e1 = expf(v.y - m), e2 = expf(v.z - m), e3 = expf(v.w - m);
    float sum = e0 + e1 + e2 + e3;
    #pragma unroll
    for (int o = 32; o > 0; o >>= 1) sum += __shfl_xor(sum, o);
    __syncthreads();
    if (lane == 0) red[4 + wv] = sum;
    __syncthreads();
    float inv = 1.f / (red[4] + red[5] + red[6] + red[7]);
    sh4 o4; o4[0] = f2bs(e0*inv); o4[1] = f2bs(e1*inv); o4[2] = f2bs(e2*inv); o4[3] = f2bs(e3*inv);
    *reinterpret_cast<sh4*>(qp + t*4) = o4;
}

// ------------------------------------------------------------------ BN stats / apply
__global__ __launch_bounds__(256) void k_stats(const float* __restrict__ in,
                                               float* __restrict__ sum, float* __restrict__ sumsq){
    int t = threadIdx.x, c0 = t*2, r0 = blockIdx.x*32;
    float s0=0, s1=0, q0=0, q1=0;
    for (int r = 0; r < 32; ++r){
        float2 v = *reinterpret_cast<const float2*>(in + (size_t)(r0+r)*C_ + c0);
        s0 += v.x; q0 += v.x*v.x; s1 += v.y; q1 += v.y*v.y;
    }
    atomicAdd(&sum[c0],   s0); atomicAdd(&sum[c0+1],   s1);
    atomicAdd(&sumsq[c0], q0); atomicAdd(&sumsq[c0+1], q1);
}

__global__ __launch_bounds__(256) void k_apply1(const float* __restrict__ fusx,
                                                const float* __restrict__ x,
                                                const float* __restrict__ sum,
                                                const float* __restrict__ sumsq,
                                                const float* __restrict__ g,
                                                const float* __restrict__ bb,
                                                const float* __restrict__ gamma,
                                                short* __restrict__ x2q){
    int idx = blockIdx.x*256 + threadIdx.x;
    int c = idx & (C_-1);
    float mean = sum[c]*(1.f/NTOK);
    float var  = sumsq[c]*(1.f/NTOK) - mean*mean;
    float t = (fusx[idx] - mean)*rsqrtf(var + EPS_)*g[c] + bb[c];
    x2q[idx] = f2bs(x[idx] + gamma[0]*fmaxf(t, 0.f));
}

__global__ __launch_bounds__(256) void k_apply2(float* __restrict__ Y,
                                                const float* __restrict__ sum,
                                                const float* __restrict__ sumsq,
                                                const float* __restrict__ g,
                                                const float* __restrict__ bb){
    int idx = blockIdx.x*256 + threadIdx.x;
    int c = idx & (C_-1);
    float mean = sum[c]*(1.f/NTOK);
    float var  = sumsq[c]*(1.f/NTOK) - mean*mean;
    float t = (Y[idx] - mean)*rsqrtf(var + EPS_)*g[c] + bb[c];
    Y[idx] = fmaxf(t, 0.f);
}

// ------------------------------------------------------------------ launch
extern "C" void kernel_launch(void* const* d_in, const int* in_sizes, int n_in,
                              void* d_out, int out_size, void* d_ws, size_t ws_size,
                              hipStream_t stream){
    const float* x      = (const float*)d_in[0];
    const float* prevx  = (const float*)d_in[1];
    const float* w_prev = (const float*)d_in[2];
    const float* w_qkv  = (const float*)d_in[3];
    const float* fuse_w = (const float*)d_in[4];
    const float* fuse_b = (const float*)d_in[5];
    const float* bn1_g  = (const float*)d_in[6];
    const float* bn1_b  = (const float*)d_in[7];
    const float* out_w  = (const float*)d_in[8];
    const float* out_b  = (const float*)d_in[9];
    const float* bn2_g  = (const float*)d_in[10];
    const float* bn2_b  = (const float*)d_in[11];
    const float* gamma  = (const float*)d_in[12];
    const float* beta   = (const float*)d_in[13];
    float* out = (float*)d_out;

    char* ws8 = (char*)d_ws;
    float* S    = (float*)(ws8 + 0);             // 67.1 MB
    short* pxq  = (short*)(ws8 + 0);             // alias (dead before scores-avg)
    short* Pq   = (short*)(ws8 + 67108864);      // 33.6 MB
    short* xq   = (short*)(ws8 + 100663296);     // 16.8 MB
    short* avgk = xq;                            // alias after qkv GEMM
    short* qkv  = (short*)(ws8 + 117440512);
    short* x2q  = qkv;                           // alias after scores-max
    short* qkvT = (short*)(ws8 + 134217728);
    short* avgkT= qkvT;                          // alias after PV-self
    short* prevT= qkvT;                          // alias after PV-avg
    short* nowT = (short*)(ws8 + 150994944);
    short* maxk = (short*)(ws8 + 167772160);
    short* maxkT= (short*)(ws8 + 184549376);
    float* fusx = (float*)(ws8 + 167772160);     // alias maxk+maxkT after PV-max
    short* avgT = (short*)(ws8 + 201326592);
    short* wqT  = (short*)(ws8 + 218103808);
    short* wpT  = (short*)(ws8 + 218628096);
    short* wfT  = (short*)(ws8 + 218890240);
    short* wcT  = (short*)(ws8 + 219938816);
    float* st   = (float*)(ws8 + 224657408);     // 2048 stats + 256 zero page floats
    short* zpg  = (short*)(ws8 + 224665600);
    float *s1sum = st, *s1sq = st + 512, *s2sum = st + 1024, *s2sq = st + 1536;

    dim3 blk(256);
    k_zero<<<9, blk, 0, stream>>>(st, 2304);
    // casts / weight transposes
    k_cast<<<8192, blk, 0, stream>>>(x, xq, 8388608);
    k_cast<<<256,  blk, 0, stream>>>(w_qkv, wqT, 262144);
    k_cast<<<128,  blk, 0, stream>>>(w_prev, wpT, 131072);
    k_tcast<<<dim3(16, 32),  blk, 0, stream>>>(fuse_w, wfT, 1024, 512);
    k_tcast<<<dim3(16, 144), blk, 0, stream>>>(out_w, wcT, 4608, 512);

    // qkv = x @ w_qkv^T  (row-major + transposed out); A big, B small -> inner-n
    k_mm<AG_ROW, EP_QKV, ORD_INNER_N, 4, 128, 1, 512, 512, 0L, 0L>
        <<<512, blk, 0, stream>>>(xq, wqT, nullptr, nullptr, nullptr,
                                  qkv, qkvT, nullptr, nullptr);
    // self attention
    k_mm<AG_ROW, EP_SCORES, ORD_INNER_M, 8, 8, 16, 1024, 512, 524288L, 524288L>
        <<<1024, blk, 0, stream>>>(qkv, qkv, nullptr, nullptr, nullptr,
                                   S, nullptr, nullptr, nullptr);
    k_softmax<<<16384, blk, 0, stream>>>(S, Pq);
    k_mm<AG_ROW, EP_PV0, ORD_INNER_M, 8, 4, 16, 1024, 1024, 524288L, 1048576L>
        <<<512, blk, 0, stream>>>(qkvT, Pq, nullptr, nullptr, nullptr,
                                  nowT, nullptr, nullptr, nullptr);
    // prev qkv + fused 2x2 pooling; A huge, B tiny -> inner-n
    k_cast<<<16384, blk, 0, stream>>>(prevx, pxq, 16777216);
    k_mm<AG_POOL, EP_POOL, ORD_INNER_N, 4, 512, 1, 512, 256, 0L, 0L>
        <<<2048, blk, 0, stream>>>(pxq, wpT, nullptr, nullptr, nullptr,
                                   avgk, avgkT, maxk, maxkT);
    // avg attention
    k_mm<AG_ROW, EP_SCORES, ORD_INNER_M, 8, 8, 16, 1024, 512, 524288L, 524288L>
        <<<1024, blk, 0, stream>>>(qkv, avgk, nullptr, nullptr, nullptr,
                                   S, nullptr, nullptr, nullptr);
    k_softmax<<<16384, blk, 0, stream>>>(S, Pq);
    k_mm<AG_ROW, EP_PV0, ORD_INNER_M, 8, 4, 16, 1024, 1024, 524288L, 1048576L>
        <<<512, blk, 0, stream>>>(avgkT, Pq, nullptr, nullptr, nullptr,
                                  avgT, nullptr, nullptr, nullptr);
    // max attention + beta-combine -> prevT
    k_mm<AG_ROW, EP_SCORES, ORD_INNER_M, 8, 8, 16, 1024, 512, 524288L, 524288L>
        <<<1024, blk, 0, stream>>>(qkv, maxk, nullptr, nullptr, nullptr,
                                   S, nullptr, nullptr, nullptr);
    k_softmax<<<16384, blk, 0, stream>>>(S, Pq);
    k_mm<AG_ROW, EP_PV1, ORD_INNER_M, 8, 4, 16, 1024, 1024, 524288L, 1048576L>
        <<<512, blk, 0, stream>>>(maxkT, Pq, nullptr, avgT, beta,
                                  prevT, nullptr, nullptr, nullptr);
    // fuse 1x1 + BN1 + residual; A = 2x16.8 MB dominant -> inner-n
    k_mm<AG_FUSE, EP_BIAS_F32, ORD_INNER_N, 4, 128, 1, 512, 1024, 0L, 0L>
        <<<512, blk, 0, stream>>>(nowT, wfT, prevT, nullptr, fuse_b,
                                  fusx, nullptr, nullptr, nullptr);
    k_stats<<<512, blk, 0, stream>>>(fusx, s1sum, s1sq);
    k_apply1<<<32768, blk, 0, stream>>>(fusx, x, s1sum, s1sq, bn1_g, bn1_b, gamma, x2q);
    // 3x3 conv (implicit GEMM) + BN2; B panel 4.7 MB dominant -> inner-m
    k_mm<AG_CONV, EP_BIAS_F32, ORD_INNER_M, 4, 128, 1, 512, 4608, 0L, 0L>
        <<<512, blk, 0, stream>>>(x2q, wcT, zpg, nullptr, out_b,
                                  out, nullptr, nullptr, nullptr);
    k_stats<<<512, blk, 0, stream>>>(out, s2sum, s2sq);
    k_apply2<<<32768, blk, 0, stream>>>(out, s2sum, s2sq, bn2_g, bn2_b);
}